// Round 1
// baseline (644.849 us; speedup 1.0000x reference)
//
#include <hip/hip_runtime.h>
#include <cstdint>
#include <cstddef>

typedef _Float16 f16;
typedef _Float16 half8 __attribute__((ext_vector_type(8)));
typedef float f32x4 __attribute__((ext_vector_type(4)));

#if defined(__has_builtin)
#  if __has_builtin(__builtin_amdgcn_global_load_lds)
#    define HAS_GLL 1
#  endif
#endif
#ifndef HAS_GLL
#  define HAS_GLL 0
#endif

typedef __attribute__((address_space(1))) const void GV;
typedef __attribute__((address_space(3))) void LV;

constexpr int CDIM = 192;      // C
constexpr int HW   = 3136;     // 56*56
constexpr int NBAT = 4;        // B
constexpr int TSTEPS = 16;     // T
constexpr int MTOT = NBAT * HW;  // 12544
constexpr int BM = 128, BK = 32;

// workspace layout (bytes)
constexpr size_t SZ_WZR   = (size_t)384 * 384 * 2;   // packed f16
constexpr size_t SZ_WH    = (size_t)192 * 384 * 2;
constexpr size_t SZ_PLANE = (size_t)MTOT * CDIM * 2; // 4,816,896
constexpr size_t OFF_WHI_ZR = 0;
constexpr size_t OFF_WLO_ZR = OFF_WHI_ZR + SZ_WZR;
constexpr size_t OFF_WHI_H  = OFF_WLO_ZR + SZ_WZR;
constexpr size_t OFF_WLO_H  = OFF_WHI_H + SZ_WH;
constexpr size_t OFF_XT     = OFF_WLO_H + SZ_WH;
constexpr size_t OFF_HT     = OFF_XT + SZ_PLANE;
constexpr size_t OFF_ZB     = OFF_HT + SZ_PLANE;
constexpr size_t OFF_RH     = OFF_ZB + SZ_PLANE;

// ---------------- weight packing: B-fragment order, hi/lo split ----------------
// B[k][n] = w[n][k]; frag idx: lane=(g<<4)|(n&15), slot i: k = kt*32+g*8+i
__global__ void pack_w(const float* __restrict__ wz, const float* __restrict__ wr,
                       const float* __restrict__ wh, char* __restrict__ ws) {
    int idx = blockIdx.x * 256 + threadIdx.x;
    const int ZRT = 384 * 384;
    int n, k, NT;
    float w;
    f16 *whi, *wlo;
    if (idx < ZRT) {
        n = idx / 384; k = idx - n * 384;
        w = (n < 192) ? wz[n * 384 + k] : wr[(n - 192) * 384 + k];
        whi = (f16*)(ws + OFF_WHI_ZR); wlo = (f16*)(ws + OFF_WLO_ZR); NT = 24;
    } else {
        int j = idx - ZRT;
        if (j >= 192 * 384) return;
        n = j / 384; k = j - n * 384;
        w = wh[n * 384 + k];
        whi = (f16*)(ws + OFF_WHI_H); wlo = (f16*)(ws + OFF_WLO_H); NT = 12;
    }
    f16 hi = (f16)w;
    f16 lo = (f16)((w - (float)hi) * 1024.0f);  // scaled to avoid f16 denorm flush
    int kt = k >> 5, g = (k >> 3) & 3, i = k & 7, nt = n >> 4;
    int lane = (g << 4) | (n & 15);
    size_t p = ((size_t)(kt * NT + nt) * 64 + lane) * 8 + i;
    whi[p] = hi; wlo[p] = lo;
}

// ---------------- x transpose: [c][hw] fp32 -> [m][c] f16 ----------------
__global__ void transpose_x(const float* __restrict__ video, f16* __restrict__ xt, int tstep) {
    __shared__ float tile[32][65];
    int b = blockIdx.z, c0 = blockIdx.y * 32, hw0 = blockIdx.x * 64;
    int t = threadIdx.x;
    const float* src = video + (size_t)(b * TSTEPS + tstep) * CDIM * HW;
#pragma unroll
    for (int it = 0; it < 2; ++it) {
        int cc = (t >> 4) + it * 16;
        int q = t & 15;
        float4 v = *(const float4*)&src[(size_t)(c0 + cc) * HW + hw0 + q * 4];
        tile[cc][q * 4 + 0] = v.x; tile[cc][q * 4 + 1] = v.y;
        tile[cc][q * 4 + 2] = v.z; tile[cc][q * 4 + 3] = v.w;
    }
    __syncthreads();
    int hw = t >> 2, cq = t & 3;
    half8 o;
#pragma unroll
    for (int j = 0; j < 8; ++j) o[j] = (f16)tile[cq * 8 + j][hw];
    *(half8*)&xt[(size_t)(b * HW + hw0 + hw) * CDIM + c0 + cq * 8] = o;
}

// ---------------- per-step GEMM + fused gate epilogue ----------------
// MODE 0 (ZR): A=[x|h](K=384), N=384 -> z=sig(.) to zb, rh=sig(.)*h to rh
// MODE 1 (H):  A=[x|rh],      N=192 -> hn=(1-z)h+z*tanh(.) to hT + dout
template <int MODE>
__global__ __launch_bounds__(256) void gemm_step(
    const f16* __restrict__ xt, const f16* __restrict__ a2,
    const f16* __restrict__ whi, const f16* __restrict__ wlo,
    const float* __restrict__ b0, const float* __restrict__ b1,
    f16* __restrict__ zb, f16* __restrict__ rh,
    const f16* __restrict__ zb_in, f16* hT, float* __restrict__ dout,
    int tstep) {
    constexpr int NREP = 2;
    constexpr int BN = 64;
    constexpr int NT = MODE ? 12 : 24;
    constexpr int EPS = BN + 8;                    // 72 f16 per row
    constexpr int SMEM = MODE ? (18432 + 33280) : 18432;
    __shared__ __align__(16) char smem[SMEM];

    const int mt = blockIdx.x, ntB = blockIdx.y;
    const int tid = threadIdx.x, wid = tid >> 6, lane = tid & 63;
    const int wm = (wid >> 1) * 64;
    const int wn = (wid & 1) * 32;
    const int l15 = lane & 15, lg = lane >> 4;

    auto stage = [&](int buf, int kt) {
#pragma unroll
        for (int j = 0; j < 2; ++j) {
            int ml = wid * 32 + j * 16 + (lane >> 2);
            int c = lane & 3;
            int g = c ^ ((ml >> 1) & 3);           // source pre-swizzle
            int kg = kt * BK + g * 8;
            const f16* srcp = (kg < CDIM)
                ? (xt + (size_t)(mt * BM + ml) * CDIM + kg)
                : (a2 + (size_t)(mt * BM + ml) * CDIM + (kg - CDIM));
#if HAS_GLL
            __builtin_amdgcn_global_load_lds((GV*)srcp,
                (LV*)(smem + buf * 8192 + (wid * 32 + j * 16) * 64), 16, 0, 0);
#else
            uint4 v = *(const uint4*)srcp;
            *(uint4*)(smem + buf * 8192 + ml * 64 + c * 16) = v;
#endif
        }
    };

    f32x4 acch[4][NREP], accl[4][NREP];
#pragma unroll
    for (int i = 0; i < 4; ++i)
#pragma unroll
        for (int r = 0; r < NREP; ++r)
#pragma unroll
            for (int q = 0; q < 4; ++q) { acch[i][r][q] = 0.f; accl[i][r][q] = 0.f; }

    stage(0, 0);
    __syncthreads();
    for (int kt = 0; kt < 12; ++kt) {
        int cur = kt & 1;
        if (kt < 11) stage(cur ^ 1, kt + 1);
        half8 bhf[NREP], blf[NREP];
#pragma unroll
        for (int r = 0; r < NREP; ++r) {
            int ntg = ntB * (BN / 16) + (wid & 1) * NREP + r;
            size_t bi = ((size_t)(kt * NT + ntg) * 64 + lane) * 8;
            bhf[r] = *(const half8*)(whi + bi);
            blf[r] = *(const half8*)(wlo + bi);
        }
        half8 af[4];
#pragma unroll
        for (int i = 0; i < 4; ++i) {
            int ml = wm + i * 16 + l15;
            int off = cur * 8192 + ml * 64 + ((lg ^ ((ml >> 1) & 3)) << 4);
            af[i] = *(const half8*)(smem + off);
        }
#pragma unroll
        for (int i = 0; i < 4; ++i)
#pragma unroll
            for (int r = 0; r < NREP; ++r) {
                acch[i][r] = __builtin_amdgcn_mfma_f32_16x16x32_f16(af[i], bhf[r], acch[i][r], 0, 0, 0);
                accl[i][r] = __builtin_amdgcn_mfma_f32_16x16x32_f16(af[i], blf[r], accl[i][r], 0, 0, 0);
            }
        __syncthreads();
    }

    // activation -> LDS tile [128][EPS] f16  (C/D map: col=lane&15, row=(lane>>4)*4+q)
    f16* ep = (f16*)smem;
#pragma unroll
    for (int i = 0; i < 4; ++i)
#pragma unroll
        for (int r = 0; r < NREP; ++r) {
            int nloc = wn + r * 16 + l15;
            int nglob = ntB * BN + nloc;
            float bias = MODE ? b0[nglob] : (nglob < CDIM ? b0[nglob] : b1[nglob - CDIM]);
#pragma unroll
            for (int q = 0; q < 4; ++q) {
                int mloc = wm + i * 16 + lg * 4 + q;
                float v = acch[i][r][q] + accl[i][r][q] * (1.0f / 1024.0f) + bias;
                float act;
                if (MODE) { float e = __expf(2.f * v); act = 1.f - 2.f / (e + 1.f); }   // tanh
                else      { act = 1.f / (1.f + __expf(-v)); }                            // sigmoid
                ep[mloc * EPS + nloc] = (f16)act;
            }
        }
    __syncthreads();

    if (MODE == 0) {
        // coalesced copy-out: z -> zb ; r*h -> rh   (both [m][c] f16)
#pragma unroll
        for (int it = 0; it < 4; ++it) {
            int row = it * 32 + (tid >> 3);
            int cq = tid & 7;
            int m = mt * BM + row;
            int cg = ntB * BN + cq * 8;
            half8 sv = *(const half8*)(ep + row * EPS + cq * 8);
            if (cg < CDIM) {
                *(half8*)(zb + (size_t)m * CDIM + cg) = sv;
            } else {
                int ch = cg - CDIM;
                half8 hv = *(const half8*)(a2 + (size_t)m * CDIM + ch);  // a2 == hT
                half8 o;
#pragma unroll
                for (int j = 0; j < 8; ++j) o[j] = (f16)((float)sv[j] * (float)hv[j]);
                *(half8*)(rh + (size_t)m * CDIM + ch) = o;
            }
        }
    } else {
        float* ep2 = (float*)(smem + 18432);   // [128][65] fp32 hn
#pragma unroll
        for (int it = 0; it < 4; ++it) {
            int row = it * 32 + (tid >> 3);
            int cq = tid & 7;
            int m = mt * BM + row;
            int cg = ntB * BN + cq * 8;
            half8 tv = *(const half8*)(ep + row * EPS + cq * 8);
            half8 zv = *(const half8*)(zb_in + (size_t)m * CDIM + cg);
            half8 hv = *(const half8*)(hT + (size_t)m * CDIM + cg);
            half8 hn16;
#pragma unroll
            for (int j = 0; j < 8; ++j) {
                float z = (float)zv[j], h = (float)hv[j], th = (float)tv[j];
                float hn = (1.f - z) * h + z * th;
                hn16[j] = (f16)hn;
                ep2[row * 65 + cq * 8 + j] = hn;
            }
            *(half8*)(hT + (size_t)m * CDIM + cg) = hn16;   // same elems read above
        }
        __syncthreads();
        // coalesced d_out write: [c][m] fp32
#pragma unroll
        for (int it = 0; it < 8; ++it) {
            int cc = tid & 63;
            int mq = (tid >> 6) + it * 4;
            int r0 = mq * 4;
            int mg = mt * BM + r0;
            int b = mg / HW;
            int hw = mg - b * HW;
            int cg = ntB * BN + cc;
            float4 o;
            o.x = ep2[(r0 + 0) * 65 + cc];
            o.y = ep2[(r0 + 1) * 65 + cc];
            o.z = ep2[(r0 + 2) * 65 + cc];
            o.w = ep2[(r0 + 3) * 65 + cc];
            *(float4*)&dout[(((size_t)b * TSTEPS + tstep) * CDIM + cg) * HW + hw] = o;
        }
    }
}

extern "C" void kernel_launch(void* const* d_in, const int* in_sizes, int n_in,
                              void* d_out, int out_size, void* d_ws, size_t ws_size,
                              hipStream_t stream) {
    const float* video = (const float*)d_in[0];
    const float* wz = (const float*)d_in[1];
    const float* bz = (const float*)d_in[2];
    const float* wr = (const float*)d_in[3];
    const float* br = (const float*)d_in[4];
    const float* wh = (const float*)d_in[5];
    const float* bh = (const float*)d_in[6];
    char* ws = (char*)d_ws;
    f16* xt = (f16*)(ws + OFF_XT);
    f16* hT = (f16*)(ws + OFF_HT);
    f16* zb = (f16*)(ws + OFF_ZB);
    f16* rh = (f16*)(ws + OFF_RH);
    const f16* whiZR = (const f16*)(ws + OFF_WHI_ZR);
    const f16* wloZR = (const f16*)(ws + OFF_WLO_ZR);
    const f16* whiH  = (const f16*)(ws + OFF_WHI_H);
    const f16* wloH  = (const f16*)(ws + OFF_WLO_H);
    float* dout = (float*)d_out;

    hipMemsetAsync(hT, 0, SZ_PLANE, stream);                 // h0 = 0
    pack_w<<<864, 256, 0, stream>>>(wz, wr, wh, ws);
    for (int t = 0; t < TSTEPS; ++t) {
        transpose_x<<<dim3(49, 6, 4), 256, 0, stream>>>(video, xt, t);
        gemm_step<0><<<dim3(98, 6), 256, 0, stream>>>(
            xt, hT, whiZR, wloZR, bz, br, zb, rh, nullptr, nullptr, nullptr, t);
        gemm_step<1><<<dim3(98, 3), 256, 0, stream>>>(
            xt, rh, whiH, wloH, bh, nullptr, nullptr, nullptr, zb, hT, dout, t);
    }
}

// Round 2
// 526.267 us; speedup vs baseline: 1.2253x; 1.2253x over previous
//
#include <hip/hip_runtime.h>
#include <cstdint>
#include <cstddef>

typedef _Float16 f16;
typedef _Float16 half8 __attribute__((ext_vector_type(8)));
typedef float f32x4 __attribute__((ext_vector_type(4)));

#if defined(__has_builtin)
#  if __has_builtin(__builtin_amdgcn_global_load_lds)
#    define HAS_GLL 1
#  endif
#endif
#ifndef HAS_GLL
#  define HAS_GLL 0
#endif

// set to 1 to re-enable the f16-lo weight-correction MFMA path (2x MFMA, ~2x accuracy)
#define USE_LO 0

typedef __attribute__((address_space(1))) const void GV;
typedef __attribute__((address_space(3))) void LV;

constexpr int CDIM = 192;      // C
constexpr int HW   = 3136;     // 56*56
constexpr int NBAT = 4;        // B
constexpr int TSTEPS = 16;     // T
constexpr int MTOT = NBAT * HW;  // 12544
constexpr int BM = 128, BK = 32;

// workspace layout (bytes) — xt plane(s) last so the 16-plane variant just extends
constexpr size_t SZ_WZR   = (size_t)384 * 384 * 2;   // packed f16
constexpr size_t SZ_WH    = (size_t)192 * 384 * 2;
constexpr size_t SZ_PLANE = (size_t)MTOT * CDIM * 2; // 4,816,896
constexpr size_t OFF_WHI_ZR = 0;
constexpr size_t OFF_WLO_ZR = OFF_WHI_ZR + SZ_WZR;
constexpr size_t OFF_WHI_H  = OFF_WLO_ZR + SZ_WZR;
constexpr size_t OFF_WLO_H  = OFF_WHI_H + SZ_WH;
constexpr size_t OFF_HT     = OFF_WLO_H + SZ_WH;     // 884736
constexpr size_t OFF_ZB     = OFF_HT + SZ_PLANE;
constexpr size_t OFF_RH     = OFF_ZB + SZ_PLANE;
constexpr size_t OFF_XT     = OFF_RH + SZ_PLANE;
constexpr size_t NEED_BIG   = OFF_XT + 16 * SZ_PLANE;   // ~88 MB
constexpr size_t NEED_SMALL = OFF_XT + SZ_PLANE;

// ---------------- weight packing: B-fragment order, hi/lo split ----------------
// B[k][n] = w[n][k]; frag idx: lane=(g<<4)|(n&15), slot i: k = kt*32+g*8+i
__global__ void pack_w(const float* __restrict__ wz, const float* __restrict__ wr,
                       const float* __restrict__ wh, char* __restrict__ ws) {
    int idx = blockIdx.x * 256 + threadIdx.x;
    const int ZRT = 384 * 384;
    int n, k, NT;
    float w;
    f16 *whi, *wlo;
    if (idx < ZRT) {
        n = idx / 384; k = idx - n * 384;
        w = (n < 192) ? wz[n * 384 + k] : wr[(n - 192) * 384 + k];
        whi = (f16*)(ws + OFF_WHI_ZR); wlo = (f16*)(ws + OFF_WLO_ZR); NT = 24;
    } else {
        int j = idx - ZRT;
        if (j >= 192 * 384) return;
        n = j / 384; k = j - n * 384;
        w = wh[n * 384 + k];
        whi = (f16*)(ws + OFF_WHI_H); wlo = (f16*)(ws + OFF_WLO_H); NT = 12;
    }
    f16 hi = (f16)w;
    f16 lo = (f16)((w - (float)hi) * 1024.0f);  // scaled to avoid f16 denorm flush
    int kt = k >> 5, g = (k >> 3) & 3, i = k & 7, nt = n >> 4;
    int lane = (g << 4) | (n & 15);
    size_t p = ((size_t)(kt * NT + nt) * 64 + lane) * 8 + i;
    whi[p] = hi; wlo[p] = lo;
}

// ---------------- x transpose: [c][hw] fp32 -> [m][c] f16 ----------------
// tstep >= 0: single plane for that step (grid.z = 4 batches)
// tstep <  0: all 16 planes at once   (grid.z = 64 = b*16+t)
__global__ void transpose_x(const float* __restrict__ video, f16* __restrict__ xt, int tstep) {
    __shared__ float tile[32][65];
    int zz = blockIdx.z;
    int b, t;
    f16* dst;
    if (tstep < 0) { b = zz >> 4; t = zz & 15; dst = xt + (size_t)t * MTOT * CDIM; }
    else           { b = zz;      t = tstep;   dst = xt; }
    int c0 = blockIdx.y * 32, hw0 = blockIdx.x * 64;
    int tid = threadIdx.x;
    const float* src = video + (size_t)(b * TSTEPS + t) * CDIM * HW;
#pragma unroll
    for (int it = 0; it < 2; ++it) {
        int cc = (tid >> 4) + it * 16;
        int q = tid & 15;
        float4 v = *(const float4*)&src[(size_t)(c0 + cc) * HW + hw0 + q * 4];
        tile[cc][q * 4 + 0] = v.x; tile[cc][q * 4 + 1] = v.y;
        tile[cc][q * 4 + 2] = v.z; tile[cc][q * 4 + 3] = v.w;
    }
    __syncthreads();
    int hw = tid >> 2, cq = tid & 3;
    half8 o;
#pragma unroll
    for (int j = 0; j < 8; ++j) o[j] = (f16)tile[cq * 8 + j][hw];
    *(half8*)&dst[(size_t)(b * HW + hw0 + hw) * CDIM + c0 + cq * 8] = o;
}

// ---------------- per-step GEMM + fused gate epilogue ----------------
// MODE 0 (ZR): A=[x|h](K=384), N=384 -> z=sig(.) to zb, rh=sig(.)*h to rh
// MODE 1 (H):  A=[x|rh],      N=192 -> hn=(1-z)h+z*tanh(.) to hT + dout
template <int MODE>
__global__ __launch_bounds__(256) void gemm_step(
    const f16* __restrict__ xt, const f16* __restrict__ a2,
    const f16* __restrict__ whi, const f16* __restrict__ wlo,
    const float* __restrict__ b0, const float* __restrict__ b1,
    f16* __restrict__ zb, f16* __restrict__ rh,
    const f16* __restrict__ zb_in, f16* hT, float* __restrict__ dout,
    int tstep) {
    constexpr int NREP = 2;
    constexpr int BN = 64;
    constexpr int NT = MODE ? 12 : 24;
    constexpr int EPS = BN + 8;                    // 72 f16 per row
    constexpr int SMEM = MODE ? (18432 + 33280) : 18432;
    __shared__ __align__(16) char smem[SMEM];

    const int mt = blockIdx.x, ntB = blockIdx.y;
    const int tid = threadIdx.x, wid = tid >> 6, lane = tid & 63;
    const int wm = (wid >> 1) * 64;
    const int wn = (wid & 1) * 32;
    const int l15 = lane & 15, lg = lane >> 4;

    auto stage = [&](int buf, int kt) {
#pragma unroll
        for (int j = 0; j < 2; ++j) {
            int ml = wid * 32 + j * 16 + (lane >> 2);
            int c = lane & 3;
            int g = c ^ ((ml >> 1) & 3);           // source pre-swizzle
            int kg = kt * BK + g * 8;
            const f16* srcp = (kg < CDIM)
                ? (xt + (size_t)(mt * BM + ml) * CDIM + kg)
                : (a2 + (size_t)(mt * BM + ml) * CDIM + (kg - CDIM));
#if HAS_GLL
            __builtin_amdgcn_global_load_lds((GV*)srcp,
                (LV*)(smem + buf * 8192 + (wid * 32 + j * 16) * 64), 16, 0, 0);
#else
            uint4 v = *(const uint4*)srcp;
            *(uint4*)(smem + buf * 8192 + ml * 64 + c * 16) = v;
#endif
        }
    };

    f32x4 acch[4][NREP];
#if USE_LO
    f32x4 accl[4][NREP];
#endif
#pragma unroll
    for (int i = 0; i < 4; ++i)
#pragma unroll
        for (int r = 0; r < NREP; ++r)
#pragma unroll
            for (int q = 0; q < 4; ++q) {
                acch[i][r][q] = 0.f;
#if USE_LO
                accl[i][r][q] = 0.f;
#endif
            }

    stage(0, 0);
    __syncthreads();
    for (int kt = 0; kt < 12; ++kt) {
        int cur = kt & 1;
        if (kt < 11) stage(cur ^ 1, kt + 1);
        half8 bhf[NREP];
#if USE_LO
        half8 blf[NREP];
#endif
#pragma unroll
        for (int r = 0; r < NREP; ++r) {
            int ntg = ntB * (BN / 16) + (wid & 1) * NREP + r;
            size_t bi = ((size_t)(kt * NT + ntg) * 64 + lane) * 8;
            bhf[r] = *(const half8*)(whi + bi);
#if USE_LO
            blf[r] = *(const half8*)(wlo + bi);
#endif
        }
        half8 af[4];
#pragma unroll
        for (int i = 0; i < 4; ++i) {
            int ml = wm + i * 16 + l15;
            int off = cur * 8192 + ml * 64 + ((lg ^ ((ml >> 1) & 3)) << 4);
            af[i] = *(const half8*)(smem + off);
        }
#pragma unroll
        for (int i = 0; i < 4; ++i)
#pragma unroll
            for (int r = 0; r < NREP; ++r) {
                acch[i][r] = __builtin_amdgcn_mfma_f32_16x16x32_f16(af[i], bhf[r], acch[i][r], 0, 0, 0);
#if USE_LO
                accl[i][r] = __builtin_amdgcn_mfma_f32_16x16x32_f16(af[i], blf[r], accl[i][r], 0, 0, 0);
#endif
            }
        __syncthreads();
    }

    // activation -> LDS tile [128][EPS] f16  (C/D map: col=lane&15, row=(lane>>4)*4+q)
    f16* ep = (f16*)smem;
#pragma unroll
    for (int i = 0; i < 4; ++i)
#pragma unroll
        for (int r = 0; r < NREP; ++r) {
            int nloc = wn + r * 16 + l15;
            int nglob = ntB * BN + nloc;
            float bias = MODE ? b0[nglob] : (nglob < CDIM ? b0[nglob] : b1[nglob - CDIM]);
#pragma unroll
            for (int q = 0; q < 4; ++q) {
                int mloc = wm + i * 16 + lg * 4 + q;
                float v = acch[i][r][q] + bias;
#if USE_LO
                v += accl[i][r][q] * (1.0f / 1024.0f);
#endif
                float act;
                if (MODE) { float e = __expf(2.f * v); act = 1.f - 2.f / (e + 1.f); }   // tanh
                else      { act = 1.f / (1.f + __expf(-v)); }                            // sigmoid
                ep[mloc * EPS + nloc] = (f16)act;
            }
        }
    __syncthreads();

    if (MODE == 0) {
        // coalesced copy-out: z -> zb ; r*h -> rh   (both [m][c] f16)
#pragma unroll
        for (int it = 0; it < 4; ++it) {
            int row = it * 32 + (tid >> 3);
            int cq = tid & 7;
            int m = mt * BM + row;
            int cg = ntB * BN + cq * 8;
            half8 sv = *(const half8*)(ep + row * EPS + cq * 8);
            if (cg < CDIM) {
                *(half8*)(zb + (size_t)m * CDIM + cg) = sv;
            } else {
                int ch = cg - CDIM;
                half8 hv = *(const half8*)(a2 + (size_t)m * CDIM + ch);  // a2 == hT
                half8 o;
#pragma unroll
                for (int j = 0; j < 8; ++j) o[j] = (f16)((float)sv[j] * (float)hv[j]);
                *(half8*)(rh + (size_t)m * CDIM + ch) = o;
            }
        }
    } else {
        float* ep2 = (float*)(smem + 18432);   // [128][65] fp32 hn
#pragma unroll
        for (int it = 0; it < 4; ++it) {
            int row = it * 32 + (tid >> 3);
            int cq = tid & 7;
            int m = mt * BM + row;
            int cg = ntB * BN + cq * 8;
            half8 tv = *(const half8*)(ep + row * EPS + cq * 8);
            half8 zv = *(const half8*)(zb_in + (size_t)m * CDIM + cg);
            half8 hv = *(const half8*)(hT + (size_t)m * CDIM + cg);
            half8 hn16;
#pragma unroll
            for (int j = 0; j < 8; ++j) {
                float z = (float)zv[j], h = (float)hv[j], th = (float)tv[j];
                float hn = (1.f - z) * h + z * th;
                hn16[j] = (f16)hn;
                ep2[row * 65 + cq * 8 + j] = hn;
            }
            *(half8*)(hT + (size_t)m * CDIM + cg) = hn16;   // same elems read above
        }
        __syncthreads();
        // coalesced d_out write: [c][m] fp32 — lanes along m (2x512B runs per instr)
#pragma unroll
        for (int it = 0; it < 8; ++it) {
            int cc = (tid >> 5) + it * 8;      // 0..63
            int q  = tid & 31;                 // m-quad 0..31
            int r0 = q * 4;
            int mg = mt * BM + r0;
            int b = mg / HW;
            int hw = mg - b * HW;
            int cg = ntB * BN + cc;
            float4 o;
            o.x = ep2[(r0 + 0) * 65 + cc];
            o.y = ep2[(r0 + 1) * 65 + cc];
            o.z = ep2[(r0 + 2) * 65 + cc];
            o.w = ep2[(r0 + 3) * 65 + cc];
            *(float4*)&dout[(((size_t)b * TSTEPS + tstep) * CDIM + cg) * HW + hw] = o;
        }
    }
}

extern "C" void kernel_launch(void* const* d_in, const int* in_sizes, int n_in,
                              void* d_out, int out_size, void* d_ws, size_t ws_size,
                              hipStream_t stream) {
    const float* video = (const float*)d_in[0];
    const float* wz = (const float*)d_in[1];
    const float* bz = (const float*)d_in[2];
    const float* wr = (const float*)d_in[3];
    const float* br = (const float*)d_in[4];
    const float* wh = (const float*)d_in[5];
    const float* bh = (const float*)d_in[6];
    char* ws = (char*)d_ws;
    f16* hT = (f16*)(ws + OFF_HT);
    f16* zb = (f16*)(ws + OFF_ZB);
    f16* rh = (f16*)(ws + OFF_RH);
    f16* xt = (f16*)(ws + OFF_XT);
    const f16* whiZR = (const f16*)(ws + OFF_WHI_ZR);
    const f16* wloZR = (const f16*)(ws + OFF_WLO_ZR);
    const f16* whiH  = (const f16*)(ws + OFF_WHI_H);
    const f16* wloH  = (const f16*)(ws + OFF_WLO_H);
    float* dout = (float*)d_out;

    const bool big = ws_size >= NEED_BIG;

    hipMemsetAsync(hT, 0, SZ_PLANE, stream);                 // h0 = 0
    pack_w<<<864, 256, 0, stream>>>(wz, wr, wh, ws);
    if (big) transpose_x<<<dim3(49, 6, 64), 256, 0, stream>>>(video, xt, -1);
    for (int t = 0; t < TSTEPS; ++t) {
        if (!big) transpose_x<<<dim3(49, 6, 4), 256, 0, stream>>>(video, xt, t);
        const f16* xtp = big ? xt + (size_t)t * MTOT * CDIM : xt;
        gemm_step<0><<<dim3(98, 6), 256, 0, stream>>>(
            xtp, hT, whiZR, wloZR, bz, br, zb, rh, nullptr, nullptr, nullptr, t);
        gemm_step<1><<<dim3(98, 3), 256, 0, stream>>>(
            xtp, rh, whiH, wloH, bh, nullptr, nullptr, nullptr, zb, hT, dout, t);
    }
}

// Round 3
// 433.135 us; speedup vs baseline: 1.4888x; 1.2150x over previous
//
#include <hip/hip_runtime.h>
#include <cstdint>
#include <cstddef>

typedef _Float16 f16;
typedef _Float16 half8 __attribute__((ext_vector_type(8)));
typedef float f32x4 __attribute__((ext_vector_type(4)));

typedef __attribute__((address_space(1))) const void GV;
typedef __attribute__((address_space(3))) void LV;

constexpr int CDIM = 192, HW = 3136, NBAT = 4, TSTEPS = 16;
constexpr int MTOT = NBAT * HW;       // 12544
constexpr int BM = 64;
constexpr int NBLK = MTOT / BM;       // 196 (49 hw-tiles per batch)

// workspace layout (bytes)
constexpr size_t OFF_WZR = 0;
constexpr size_t SZ_WZR  = (size_t)384 * 384 * 2;      // 294912
constexpr size_t OFF_WH  = OFF_WZR + SZ_WZR;
constexpr size_t SZ_WH   = (size_t)192 * 384 * 2;      // 147456
constexpr size_t OFF_HT  = OFF_WH + SZ_WH;             // hT: swizzled 24KB block images
constexpr size_t SZ_HT   = (size_t)MTOT * CDIM * 2;    // 4816896

// ---------------- weight packing into B-fragment order ----------------
// B[k][n] = w[n][k]; frag: lane=(g<<4)|(n&15), slot i -> k = kt*32+g*8+i
__global__ void pack_w(const float* __restrict__ wz, const float* __restrict__ wr,
                       const float* __restrict__ wh, char* __restrict__ ws) {
    int idx = blockIdx.x * 256 + threadIdx.x;
    const int ZRT = 384 * 384;
    int n, k, NT;
    float w;
    f16* dst;
    if (idx < ZRT) {
        n = idx / 384; k = idx - n * 384;
        w = (n < 192) ? wz[n * 384 + k] : wr[(n - 192) * 384 + k];
        dst = (f16*)(ws + OFF_WZR); NT = 24;
    } else {
        int j = idx - ZRT;
        if (j >= 192 * 384) return;
        n = j / 384; k = j - n * 384;
        w = wh[n * 384 + k];
        dst = (f16*)(ws + OFF_WH); NT = 12;
    }
    int kt = k >> 5, g = (k >> 3) & 3, i = k & 7, nt = n >> 4;
    int lane = (g << 4) | (n & 15);
    dst[((size_t)(kt * NT + nt) * 64 + lane) * 8 + i] = (f16)w;
}

// ---------------- fused per-step kernel ----------------
// Block: 64 rows (one hw-tile of one batch) x full N. 4 waves: (w>>1)=m-half, (w&1)=n-half.
// LDS tiles [64][192] f16, row stride 384B, XOR-swizzle ((row&7)<<4) on in-row byte.
__global__ __launch_bounds__(256, 2) void gru_step(
    const float* __restrict__ video,
    const f16* __restrict__ wZR, const f16* __restrict__ wH,
    const float* __restrict__ bz, const float* __restrict__ br,
    const float* __restrict__ bh,
    f16* __restrict__ hT, float* __restrict__ dout, int t) {
    __shared__ __align__(16) char smem[73728];
    char* AX = smem;            // [64][192] x   (k 0..191)
    char* AH = smem + 24576;    // [64][192] h   (k 192..383)
    char* RH = smem + 49152;    // [64][192] r*h, later h_new
    const int tid = threadIdx.x, w = tid >> 6, lane = tid & 63;
    const int l15 = lane & 15, lg = lane >> 4;
    const int mt = blockIdx.x, bb = mt / 49, hw0 = (mt % 49) * 64;
    const int wm = (w >> 1) * 32, nw = w & 1;
    const int slot = (l15 & 7) << 4;

    // ---- stage h: global_load_lds, hT is a linear image of the swizzled tile ----
    {
        const f16* hsrc = hT + (size_t)mt * 12288 + w * 3072 + lane * 8;
#pragma unroll
        for (int i = 0; i < 6; ++i)
            __builtin_amdgcn_global_load_lds((GV*)(hsrc + i * 512),
                                             (LV*)(AH + w * 6144 + i * 1024), 16, 0, 0);
    }
    // ---- stage x: fp32 video [c][hw] -> f16 swizzled [hw][c] ----
    {
        const float* vs = video + ((size_t)(bb * TSTEPS + t) * CDIM) * HW + hw0 + lane;
        int sl = (lane & 7) << 4;
#pragma unroll
        for (int i = 0; i < 6; ++i) {
            int c0 = (i * 4 + w) * 8;
            half8 hv;
#pragma unroll
            for (int j = 0; j < 8; ++j) hv[j] = (f16)vs[(size_t)(c0 + j) * HW];
            *(half8*)(AX + lane * 384 + ((2 * c0) ^ sl)) = hv;
        }
    }
    float vbz[6], vbr[6], vbh[6];
#pragma unroll
    for (int r = 0; r < 6; ++r) {
        int c = nw * 96 + r * 16 + l15;
        vbz[r] = bz[c]; vbr[r] = br[c]; vbh[r] = bh[c];
    }
    __syncthreads();

    // ---- ZR GEMM: barrier-free K-loop (A in LDS, B streamed from L2) ----
    f32x4 az[2][6], ar[2][6];
#pragma unroll
    for (int i = 0; i < 2; ++i)
#pragma unroll
        for (int r = 0; r < 6; ++r)
#pragma unroll
            for (int q = 0; q < 4; ++q) { az[i][r][q] = 0.f; ar[i][r][q] = 0.f; }
#pragma unroll
    for (int kt = 0; kt < 12; ++kt) {
        const char* ab = (kt < 6) ? AX : AH;
        int kb = (kt % 6) * 64 + lg * 16;
        half8 a0 = *(const half8*)(ab + (wm + l15) * 384 + (kb ^ slot));
        half8 a1 = *(const half8*)(ab + (wm + 16 + l15) * 384 + (kb ^ slot));
#pragma unroll
        for (int r = 0; r < 6; ++r) {
            half8 bzf = *(const half8*)(wZR + ((size_t)(kt * 24 + nw * 6 + r) * 64 + lane) * 8);
            half8 brf = *(const half8*)(wZR + ((size_t)(kt * 24 + 12 + nw * 6 + r) * 64 + lane) * 8);
            az[0][r] = __builtin_amdgcn_mfma_f32_16x16x32_f16(a0, bzf, az[0][r], 0, 0, 0);
            az[1][r] = __builtin_amdgcn_mfma_f32_16x16x32_f16(a1, bzf, az[1][r], 0, 0, 0);
            ar[0][r] = __builtin_amdgcn_mfma_f32_16x16x32_f16(a0, brf, ar[0][r], 0, 0, 0);
            ar[1][r] = __builtin_amdgcn_mfma_f32_16x16x32_f16(a1, brf, ar[1][r], 0, 0, 0);
        }
    }
    // ---- r*h -> RH (z stays in registers) ----
#pragma unroll
    for (int i = 0; i < 2; ++i)
#pragma unroll
        for (int r = 0; r < 6; ++r)
#pragma unroll
            for (int q = 0; q < 4; ++q) {
                int row = wm + i * 16 + lg * 4 + q;
                int cb = 2 * (nw * 96 + r * 16 + l15);
                int sw = (row & 7) << 4;
                float rg = 1.f / (1.f + __expf(-(ar[i][r][q] + vbr[r])));
                float hv = (float)*(const f16*)(AH + row * 384 + (cb ^ sw));
                *(f16*)(RH + row * 384 + (cb ^ sw)) = (f16)(rg * hv);
            }
    __syncthreads();

    // ---- H GEMM: A = [x | r*h] ----
    f32x4 ac[2][6];
#pragma unroll
    for (int i = 0; i < 2; ++i)
#pragma unroll
        for (int r = 0; r < 6; ++r)
#pragma unroll
            for (int q = 0; q < 4; ++q) ac[i][r][q] = 0.f;
#pragma unroll
    for (int kt = 0; kt < 12; ++kt) {
        const char* ab = (kt < 6) ? AX : RH;
        int kb = (kt % 6) * 64 + lg * 16;
        half8 a0 = *(const half8*)(ab + (wm + l15) * 384 + (kb ^ slot));
        half8 a1 = *(const half8*)(ab + (wm + 16 + l15) * 384 + (kb ^ slot));
#pragma unroll
        for (int r = 0; r < 6; ++r) {
            half8 bf = *(const half8*)(wH + ((size_t)(kt * 12 + nw * 6 + r) * 64 + lane) * 8);
            ac[0][r] = __builtin_amdgcn_mfma_f32_16x16x32_f16(a0, bf, ac[0][r], 0, 0, 0);
            ac[1][r] = __builtin_amdgcn_mfma_f32_16x16x32_f16(a1, bf, ac[1][r], 0, 0, 0);
        }
    }
    __syncthreads();   // all waves done reading RH; safe to overwrite with h_new

    // ---- epilogue: h_new = (1-z)h + z*tanh(.) -> RH ----
#pragma unroll
    for (int i = 0; i < 2; ++i)
#pragma unroll
        for (int r = 0; r < 6; ++r)
#pragma unroll
            for (int q = 0; q < 4; ++q) {
                int row = wm + i * 16 + lg * 4 + q;
                int cb = 2 * (nw * 96 + r * 16 + l15);
                int sw = (row & 7) << 4;
                float zg = 1.f / (1.f + __expf(-(az[i][r][q] + vbz[r])));
                float e = __expf(2.f * (ac[i][r][q] + vbh[r]));
                float th = 1.f - 2.f / (e + 1.f);
                float hold = (float)*(const f16*)(AH + row * 384 + (cb ^ sw));
                *(f16*)(RH + row * 384 + (cb ^ sw)) = (f16)((1.f - zg) * hold + zg * th);
            }
    __syncthreads();

    // ---- writeout ----
    {
        // hT: linear byte image of swizzled tile (coalesced, matches next-step gll staging)
        f16* hdst = hT + (size_t)mt * 12288;
#pragma unroll
        for (int i = 0; i < 6; ++i) {
            int e = i * 256 + tid;
            *(half8*)(hdst + e * 8) = *(const half8*)(RH + e * 16);
        }
        // dout [b][t][c][hw] fp32: lanes along hw (256B runs)
        float* db = dout + ((size_t)(bb * TSTEPS + t) * CDIM) * HW + hw0 + lane;
        int sl = (lane & 7) << 4;
#pragma unroll
        for (int j = 0; j < 48; ++j) {
            int c = j * 4 + w;
            f16 hv = *(const f16*)(RH + lane * 384 + ((2 * c) ^ sl));
            db[(size_t)c * HW] = (float)hv;
        }
    }
}

extern "C" void kernel_launch(void* const* d_in, const int* in_sizes, int n_in,
                              void* d_out, int out_size, void* d_ws, size_t ws_size,
                              hipStream_t stream) {
    const float* video = (const float*)d_in[0];
    const float* wz = (const float*)d_in[1];
    const float* bz = (const float*)d_in[2];
    const float* wr = (const float*)d_in[3];
    const float* br = (const float*)d_in[4];
    const float* wh = (const float*)d_in[5];
    const float* bh = (const float*)d_in[6];
    char* ws = (char*)d_ws;
    const f16* wZR = (const f16*)(ws + OFF_WZR);
    const f16* wHp = (const f16*)(ws + OFF_WH);
    f16* hT = (f16*)(ws + OFF_HT);
    float* dout = (float*)d_out;

    hipMemsetAsync(hT, 0, SZ_HT, stream);   // h0 = 0 (zeros are layout-invariant)
    pack_w<<<864, 256, 0, stream>>>(wz, wr, wh, ws);
    for (int t = 0; t < TSTEPS; ++t) {
        gru_step<<<NBLK, 256, 0, stream>>>(video, wZR, wHp, bz, br, bh, hT, dout, t);
    }
}